// Round 5
// baseline (303.402 us; speedup 1.0000x reference)
//
#include <hip/hip_runtime.h>
#include <hip/hip_bf16.h>

typedef __attribute__((ext_vector_type(8))) __bf16 bf16x8;
typedef __attribute__((ext_vector_type(4))) float f32x4;
typedef unsigned short ushort_t;
typedef unsigned int uint_t;

#define CCH 256
#define BB 4

__device__ __forceinline__ ushort_t f2b(float v) {
    __hip_bfloat16 h = __float2bfloat16(v);
    return *reinterpret_cast<ushort_t*>(&h);
}

__device__ __forceinline__ void gload16(const void* g, void* l) {
    __builtin_amdgcn_global_load_lds(
        (const __attribute__((address_space(1))) void*)g,
        (__attribute__((address_space(3))) void*)l, 16, 0, 0);
}

struct PrepPtrs {
    ushort_t* o0; ushort_t* o1; ushort_t* o2; ushort_t* o3;
    float* n0; float* n1; float* n2; float* n3;
};

// =====================================================================
// pyr_prep v2: ONE pass, [channel][pixel+pad] LDS (stride 260/68/20,
// all ≡0 mod 4). Stage = b128 writes at structural-minimum banking
// (c wave-uniform -> banks 4c+4*x4 cover all 32). Transpose read =
// scalar b32, 2-way (free). Pooling = aligned b64, ~min banking.
// Block = (b, 8-row stripe, 32-col chunk) of L0; 8 kc chunks of 32ch.
// =====================================================================
__global__ __launch_bounds__(256, 3) void pyr_prep_kernel(
    const float* __restrict__ fa, const float* __restrict__ fb,
    PrepPtrs Pa, PrepPtrs Pb)
{
    const int H = 128, W = 192;
    const int HW = H * W;
    const float* fin = blockIdx.y ? fb : fa;
    PrepPtrs P = blockIdx.y ? Pb : Pa;

    __shared__ float lds0[32 * 260];   // [c:32][p:256 pad->260]
    __shared__ float lds1[32 * 68];    // [c:32][q:64 pad->68]
    __shared__ float lds2[32 * 20];    // [c:32][s:16 pad->20]
    __shared__ float red[256];

    int xc = blockIdx.x % 6;
    int ys = (blockIdx.x / 6) % 16;
    int b  = blockIdx.x / 96;
    int gx0 = xc * 32, gy0 = ys * 8;
    int t = threadIdx.x;

    // staging decode (hoisted): e = t + 256*j -> c = e>>6, r=(e>>3)&7, x4=e&7
    const float* gsrc[8];
    int lofs[8];
    #pragma unroll
    for (int j = 0; j < 8; ++j) {
        int e = t + 256 * j;
        int c = e >> 6, r = (e >> 3) & 7, x4 = e & 7;
        gsrc[j] = fin + ((size_t)(b * 256 + c) * H + gy0 + r) * W + gx0 + 4 * x4;
        lofs[j] = c * 260 + r * 32 + 4 * x4;
    }

    float4 stg[8];
    auto issue = [&](int kc) {
        #pragma unroll
        for (int j = 0; j < 8; ++j)
            stg[j] = *reinterpret_cast<const float4*>(gsrc[j] + (size_t)kc * (32 * HW));
    };

    float ssq0 = 0.f, ssq1 = 0.f, ssq2 = 0.f, ssq3 = 0.f;

    // per-level owners
    size_t p0g = (size_t)(b * H + gy0 + (t >> 5)) * W + gx0 + (t & 31);     // L0: pixel t
    int wv = t >> 6, q = t & 63, qy = q >> 4, qx = q & 15;                  // L1: (8ch, q)
    size_t l1g = (size_t)(b * 64 + ys * 4 + qy) * 96 + xc * 16 + qx;
    int cb2 = t >> 4, sI = t & 15, sy2 = sI >> 3, sx2 = sI & 7;             // L2 (t<128)
    size_t l2g = (size_t)(b * 32 + ys * 2 + sy2) * 48 + xc * 8 + sx2;
    int cb3 = t >> 2, u3 = t & 3;                                           // L3 (t<32)
    size_t l3g = (size_t)(b * 16 + ys) * 24 + xc * 4 + u3;

    issue(0);
    #pragma unroll 1
    for (int kc = 0; kc < 8; ++kc) {
        // ---- A: regs -> lds0 (8x b128, conflict-free) ----
        #pragma unroll
        for (int j = 0; j < 8; ++j)
            *reinterpret_cast<float4*>(&lds0[lofs[j]]) = stg[j];
        if (kc < 7) issue(kc + 1);   // prefetch hides under phases + barriers
        __syncthreads();

        // ---- B: L0 bf16 NHWC + ssq0 (thread owns pixel t) ----
        {
            uint_t uu[16];
            #pragma unroll
            for (int i = 0; i < 16; ++i) {
                float va = lds0[(2 * i) * 260 + t];
                float vb = lds0[(2 * i + 1) * 260 + t];
                ssq0 = fmaf(va, va, ssq0);
                ssq0 = fmaf(vb, vb, ssq0);
                uu[i] = (uint_t)f2b(va) | ((uint_t)f2b(vb) << 16);
            }
            ushort_t* dst = P.o0 + p0g * CCH + kc * 32;
            *reinterpret_cast<uint4*>(dst +  0) = make_uint4(uu[0],  uu[1],  uu[2],  uu[3]);
            *reinterpret_cast<uint4*>(dst +  8) = make_uint4(uu[4],  uu[5],  uu[6],  uu[7]);
            *reinterpret_cast<uint4*>(dst + 16) = make_uint4(uu[8],  uu[9],  uu[10], uu[11]);
            *reinterpret_cast<uint4*>(dst + 24) = make_uint4(uu[12], uu[13], uu[14], uu[15]);
        }

        // ---- L1: 2x2 pool (thread owns 8ch x 1 L1-pixel) ----
        {
            float a8[8];
            #pragma unroll
            for (int h = 0; h < 8; ++h) {
                int c = wv * 8 + h;
                float2 s0 = *reinterpret_cast<const float2*>(&lds0[c * 260 + (2 * qy) * 32 + 2 * qx]);
                float2 s1 = *reinterpret_cast<const float2*>(&lds0[c * 260 + (2 * qy + 1) * 32 + 2 * qx]);
                a8[h] = 0.25f * (s0.x + s0.y + s1.x + s1.y);
                ssq1 = fmaf(a8[h], a8[h], ssq1);
            }
            uint_t vv[4];
            #pragma unroll
            for (int i = 0; i < 4; ++i)
                vv[i] = (uint_t)f2b(a8[2 * i]) | ((uint_t)f2b(a8[2 * i + 1]) << 16);
            *reinterpret_cast<uint4*>(P.o1 + l1g * CCH + kc * 32 + wv * 8)
                = make_uint4(vv[0], vv[1], vv[2], vv[3]);
            #pragma unroll
            for (int h = 0; h < 8; ++h)
                lds1[(wv * 8 + h) * 68 + q] = a8[h];
        }
        __syncthreads();

        // ---- L2: 2x2 pool (t<128: 4ch x 1 L2-pixel) ----
        if (t < 128) {
            float a4[4];
            #pragma unroll
            for (int cc = 0; cc < 4; ++cc) {
                int c = cb2 * 4 + cc;
                float2 s0 = *reinterpret_cast<const float2*>(&lds1[c * 68 + (2 * sy2) * 16 + 2 * sx2]);
                float2 s1 = *reinterpret_cast<const float2*>(&lds1[c * 68 + (2 * sy2 + 1) * 16 + 2 * sx2]);
                a4[cc] = 0.25f * (s0.x + s0.y + s1.x + s1.y);
                ssq2 = fmaf(a4[cc], a4[cc], ssq2);
            }
            uint_t w0 = (uint_t)f2b(a4[0]) | ((uint_t)f2b(a4[1]) << 16);
            uint_t w1 = (uint_t)f2b(a4[2]) | ((uint_t)f2b(a4[3]) << 16);
            *reinterpret_cast<uint2*>(P.o2 + l2g * CCH + kc * 32 + cb2 * 4) = make_uint2(w0, w1);
            #pragma unroll
            for (int cc = 0; cc < 4; ++cc)
                lds2[(cb2 * 4 + cc) * 20 + sI] = a4[cc];
        }
        __syncthreads();

        // ---- L3: 2x2 pool (t<32: 4ch x 1 L3-pixel) ----
        if (t < 32) {
            float a4[4];
            #pragma unroll
            for (int cc = 0; cc < 4; ++cc) {
                int c = cb3 * 4 + cc;
                float2 s0 = *reinterpret_cast<const float2*>(&lds2[c * 20 + 2 * u3]);
                float2 s1 = *reinterpret_cast<const float2*>(&lds2[c * 20 + 8 + 2 * u3]);
                a4[cc] = 0.25f * (s0.x + s0.y + s1.x + s1.y);
                ssq3 = fmaf(a4[cc], a4[cc], ssq3);
            }
            uint_t w0 = (uint_t)f2b(a4[0]) | ((uint_t)f2b(a4[1]) << 16);
            uint_t w1 = (uint_t)f2b(a4[2]) | ((uint_t)f2b(a4[3]) << 16);
            *reinterpret_cast<uint2*>(P.o3 + l3g * CCH + kc * 32 + cb3 * 4) = make_uint2(w0, w1);
        }
        // next-iter A is safe: lds0 readers (B/L1) finished before sync2;
        // L2'/L1' writers gated by sync1' which L3 threads must reach.
    }

    // ---- invnorm reductions ----
    P.n0[p0g] = 1.f / fmaxf(sqrtf(ssq0), 1e-12f);
    red[t] = ssq1;
    __syncthreads();
    if (t < 64) {
        float sm = red[t] + red[t + 64] + red[t + 128] + red[t + 192];
        P.n1[(size_t)(b * 64 + ys * 4 + (t >> 4)) * 96 + xc * 16 + (t & 15)]
            = 1.f / fmaxf(sqrtf(sm), 1e-12f);
    }
    __syncthreads();
    if (t < 128) red[t] = ssq2;
    __syncthreads();
    if (t < 16) {
        float sm = 0.f;
        #pragma unroll
        for (int c = 0; c < 8; ++c) sm += red[t + 16 * c];
        P.n2[(size_t)(b * 32 + ys * 2 + (t >> 3)) * 48 + xc * 8 + (t & 7)]
            = 1.f / fmaxf(sqrtf(sm), 1e-12f);
    }
    __syncthreads();
    if (t < 32) red[t] = ssq3;
    __syncthreads();
    if (t < 4) {
        float sm = 0.f;
        #pragma unroll
        for (int c = 0; c < 8; ++c) sm += red[t + 4 * c];
        P.n3[(size_t)(b * 16 + ys) * 24 + xc * 4 + t]
            = 1.f / fmaxf(sqrtf(sm), 1e-12f);
    }
}

// =====================================================================
// corr_mfma2: LDS-staged, double-buffered (unchanged, proven)
// =====================================================================
__global__ __launch_bounds__(256, 2) void corr_mfma2_kernel(
    const ushort_t* __restrict__ f1n, const ushort_t* __restrict__ f2n,
    const float* __restrict__ invn1, const float* __restrict__ invn2,
    const float* __restrict__ dt, float* __restrict__ out,
    const ushort_t* __restrict__ zblk, int H, int W, int TX, int TY)
{
    __shared__ char smem[65536];
    char* As = smem;
    char* Bs = smem + 16384;

    int bid = blockIdx.x;
    int cpx = gridDim.x >> 3;
    int swz = (bid & 7) * cpx + (bid >> 3);
    int tx = swz % TX;
    int ty = (swz / TX) % TY;
    int b  = swz / (TX * TY);
    int x0 = tx * 16, y0 = ty * 8;

    int tid = threadIdx.x;
    int w = tid >> 6, lane = tid & 63;
    int kg = lane >> 4, col = lane & 15;
    int r2 = col >> 2, c2 = col & 3;
    int sy = w >> 1, p = w & 1;

    const ushort_t* srcA[2]; char* ldsA[2];
    #pragma unroll
    for (int q = 0; q < 2; ++q) {
        int qq = w * 2 + q;
        int kgs = qq >> 1, reg = qq & 1;
        int slot = reg * 64 + lane;
        int ly = slot >> 4, lxp = slot & 15;
        int lx = lxp ^ (4 * (ly & 1));
        srcA[q] = f1n + ((size_t)((b * H + y0 + ly) * W) + x0 + lx) * CCH + kgs * 8;
        ldsA[q] = As + qq * 1024;
    }
    const ushort_t* srcB[6]; int advB[6]; char* ldsB[6];
    #pragma unroll
    for (int q = 0; q < 6; ++q) {
        int qq = w * 6 + q;
        int kgs = qq / 6, reg = qq % 6;
        int slot = reg * 64 + lane;
        int wy = slot / 24, wxp = slot % 24;
        int wx = wxp ^ (4 * (wy & 1));
        int py = y0 - 4 + wy, px = x0 - 4 + wx;
        bool v = (py >= 0) && (py < H) && (px >= 0) && (px < W);
        srcB[q] = v ? (f2n + ((size_t)((b * H + py) * W) + px) * CCH + kgs * 8) : zblk;
        advB[q] = v ? 32 : 0;
        ldsB[q] = Bs + qq * 1024;
    }

    int aoff[2], boff[3][4];
    #pragma unroll
    for (int s = 0; s < 2; ++s) {
        int sxs = 2 * p + s;
        int ly = 4 * sy + r2;
        int lx = (4 * sxs + c2) ^ (4 * (ly & 1));
        aoff[s] = kg * 2048 + (ly * 16 + lx) * 16;
    }
    #pragma unroll
    for (int i = 0; i < 3; ++i)
        #pragma unroll
        for (int j = 0; j < 4; ++j) {
            int wy = 4 * (sy + i) + r2;
            int wx = (4 * (2 * p + j) + c2) ^ (4 * (wy & 1));
            boff[i][j] = kg * 6144 + (wy * 24 + wx) * 16;
        }

    f32x4 acc0[3][3] = {};
    f32x4 acc1[3][3] = {};

    #pragma unroll
    for (int q = 0; q < 2; ++q) { gload16(srcA[q], ldsA[q]); srcA[q] += 32; }
    #pragma unroll
    for (int q = 0; q < 6; ++q) { gload16(srcB[q], ldsB[q]); srcB[q] += advB[q]; }
    asm volatile("s_waitcnt vmcnt(0)" ::: "memory");
    __builtin_amdgcn_s_barrier();
    __builtin_amdgcn_sched_barrier(0);

    int buf = 0;
    #pragma unroll 1
    for (int kc = 0; kc < 8; ++kc) {
        if (kc < 7) {
            int boA = (buf ^ 1) * 8192;
            int boB = (buf ^ 1) * 24576;
            #pragma unroll
            for (int q = 0; q < 2; ++q) { gload16(srcA[q], ldsA[q] + boA); srcA[q] += 32; }
            #pragma unroll
            for (int q = 0; q < 6; ++q) { gload16(srcB[q], ldsB[q] + boB); srcB[q] += advB[q]; }
        }
        const char* Ab = As + buf * 8192;
        const char* Bb = Bs + buf * 24576;
        bf16x8 av0 = *(const bf16x8*)(Ab + aoff[0]);
        bf16x8 av1 = *(const bf16x8*)(Ab + aoff[1]);
        #pragma unroll
        for (int i = 0; i < 3; ++i) {
            #pragma unroll
            for (int j = 0; j < 4; ++j) {
                bf16x8 bv = *(const bf16x8*)(Bb + boff[i][j]);
                if (j < 3) acc0[i][j]     = __builtin_amdgcn_mfma_f32_16x16x32_bf16(av0, bv, acc0[i][j], 0, 0, 0);
                if (j > 0) acc1[i][j - 1] = __builtin_amdgcn_mfma_f32_16x16x32_bf16(av1, bv, acc1[i][j - 1], 0, 0, 0);
            }
        }
        if (kc < 7) {
            __builtin_amdgcn_sched_barrier(0);
            asm volatile("s_waitcnt vmcnt(0)" ::: "memory");
            __builtin_amdgcn_s_barrier();
            __builtin_amdgcn_sched_barrier(0);
        }
        buf ^= 1;
    }

    float inv1v[2][4], dtv[2][4];
    #pragma unroll
    for (int s = 0; s < 2; ++s) {
        int sxs = 2 * p + s;
        #pragma unroll
        for (int rr = 0; rr < 4; ++rr) {
            int m = kg * 4 + rr;
            int iy = m >> 2, ix = m & 3;
            int pix = (b * H + y0 + 4 * sy + iy) * W + x0 + 4 * sxs + ix;
            inv1v[s][rr] = invn1[pix];
            dtv[s][rr]   = dt[pix];
        }
    }
    #pragma unroll
    for (int s = 0; s < 2; ++s) {
        int sxs = 2 * p + s;
        #pragma unroll
        for (int i = 0; i < 3; ++i) {
            #pragma unroll
            for (int jj = 0; jj < 3; ++jj) {
                int wy = 4 * (sy + i) + r2;
                int wxr = 4 * (sxs + jj) + c2;
                int py = y0 - 4 + wy, px = x0 - 4 + wxr;
                bool v = (py >= 0) && (py < H) && (px >= 0) && (px < W);
                float i2 = v ? invn2[(b * H + py) * W + px] : 0.f;
                f32x4 a = (s == 0) ? acc0[i][jj] : acc1[i][jj];
                #pragma unroll
                for (int rr = 0; rr < 4; ++rr) {
                    int m = kg * 4 + rr;
                    int iy = m >> 2, ix = m & 3;
                    int oy = iy + 8 - (4 * i + r2);
                    int ox = ix + 8 - (4 * jj + c2);
                    if (oy >= 0 && oy < 9 && ox >= 0 && ox < 9) {
                        int gy = y0 + 4 * sy + iy, gx = x0 + 4 * sxs + ix;
                        out[((size_t)(b * 81 + oy * 9 + ox) * H + gy) * W + gx]
                            = a[rr] * inv1v[s][rr] * i2 + dtv[s][rr];
                    }
                }
            }
        }
    }
}

// =====================================================================
// corr_mfma (round-2, known good) — L3 only
// =====================================================================
__global__ __launch_bounds__(256) void corr_mfma_kernel(
    const ushort_t* __restrict__ f1n, const ushort_t* __restrict__ f2n,
    const float* __restrict__ invn1, const float* __restrict__ invn2,
    const float* __restrict__ dt, float* __restrict__ out,
    int H, int W, int TX, int TY, int zoff)
{
    int wid  = threadIdx.x >> 6;
    int lane = threadIdx.x & 63;
    int tile = blockIdx.x * 4 + wid;
    int ntiles = BB * TY * TX;
    if (tile >= ntiles) return;
    int tx = tile % TX;
    int ty = (tile / TX) % TY;
    int b  = tile / (TX * TY);
    int x0 = tx * 4, y0 = ty * 4;

    int col = lane & 15;
    int kg  = lane >> 4;

    int iyA = col >> 2, ixA = col & 3;
    int a_off = (((b * H + y0 + iyA) * W) + x0 + ixA) * CCH + kg * 8;

    int b_off[9];
    uint_t vmask = 0;
    #pragma unroll
    for (int tt = 0; tt < 9; ++tt) {
        int w = tt * 16 + col;
        int wy = w / 12, wx = w % 12;
        int py = y0 + wy - 4, px = x0 + wx - 4;
        bool v = (py >= 0) && (py < H) && (px >= 0) && (px < W);
        b_off[tt] = v ? (((b * H + py) * W + px) * CCH + kg * 8) : (zoff + kg * 8);
        if (v) vmask |= (1u << tt);
    }

    f32x4 acc[9] = {};
    #pragma unroll
    for (int kb = 0; kb < 8; ++kb) {
        bf16x8 av = *reinterpret_cast<const bf16x8*>(f1n + a_off + kb * 32);
        #pragma unroll
        for (int tt = 0; tt < 9; ++tt) {
            bf16x8 bv = *reinterpret_cast<const bf16x8*>(f2n + b_off[tt] + kb * 32);
            acc[tt] = __builtin_amdgcn_mfma_f32_16x16x32_bf16(av, bv, acc[tt], 0, 0, 0);
        }
    }

    float inv1[4], dts[4];
    #pragma unroll
    for (int r = 0; r < 4; ++r) {
        int m = kg * 4 + r;
        int iy = m >> 2, ix = m & 3;
        int pix = (b * H + y0 + iy) * W + x0 + ix;
        inv1[r] = invn1[pix];
        dts[r]  = dt[pix];
    }
    #pragma unroll
    for (int tt = 0; tt < 9; ++tt) {
        int w = tt * 16 + col;
        int wy = w / 12, wx = w % 12;
        int py = y0 + wy - 4, px = x0 + wx - 4;
        float i2 = ((vmask >> tt) & 1u) ? invn2[(b * H + py) * W + px] : 0.f;
        #pragma unroll
        for (int r = 0; r < 4; ++r) {
            int m = kg * 4 + r;
            int iy = m >> 2, ix = m & 3;
            int oy = iy + 8 - wy, ox = ix + 8 - wx;
            if (oy >= 0 && oy < 9 && ox >= 0 && ox < 9) {
                int o = oy * 9 + ox;
                out[((size_t)(b * 81 + o) * H + (y0 + iy)) * W + (x0 + ix)]
                    = acc[tt][r] * inv1[r] * i2 + dts[r];
            }
        }
    }
}

// =====================================================================
// depth: one thread owns an 8x8 L0 patch; dt for all 4 levels
// =====================================================================
__global__ __launch_bounds__(256) void depth_kernel(
    const float* __restrict__ d1, const float* __restrict__ d2,
    const float* __restrict__ dw,
    float* __restrict__ dt0, float* __restrict__ dt1,
    float* __restrict__ dt2, float* __restrict__ dt3)
{
    int rid = blockIdx.x * 256 + threadIdx.x;
    if (rid >= 4 * 16 * 24) return;
    int b = rid / 384, rr = rid % 384, ry = rr / 24, rx = rr % 24;
    const int H = 128, W = 192;
    float w0 = dw[0];
    size_t base0 = ((size_t)b * H + ry * 8) * W + rx * 8;

    float q1[4][4], q2[4][4];
    #pragma unroll
    for (int yy = 0; yy < 4; ++yy) {
        float4 a0 = *reinterpret_cast<const float4*>(d1 + base0 + (2 * yy) * W);
        float4 a1 = *reinterpret_cast<const float4*>(d1 + base0 + (2 * yy) * W + 4);
        float4 a2 = *reinterpret_cast<const float4*>(d1 + base0 + (2 * yy + 1) * W);
        float4 a3 = *reinterpret_cast<const float4*>(d1 + base0 + (2 * yy + 1) * W + 4);
        float4 b0 = *reinterpret_cast<const float4*>(d2 + base0 + (2 * yy) * W);
        float4 b1 = *reinterpret_cast<const float4*>(d2 + base0 + (2 * yy) * W + 4);
        float4 b2 = *reinterpret_cast<const float4*>(d2 + base0 + (2 * yy + 1) * W);
        float4 b3 = *reinterpret_cast<const float4*>(d2 + base0 + (2 * yy + 1) * W + 4);
        float ra[2][8] = {{a0.x,a0.y,a0.z,a0.w,a1.x,a1.y,a1.z,a1.w},
                          {a2.x,a2.y,a2.z,a2.w,a3.x,a3.y,a3.z,a3.w}};
        float rb[2][8] = {{b0.x,b0.y,b0.z,b0.w,b1.x,b1.y,b1.z,b1.w},
                          {b2.x,b2.y,b2.z,b2.w,b3.x,b3.y,b3.z,b3.w}};
        #pragma unroll
        for (int e = 0; e < 2; ++e) {
            float o[8];
            #pragma unroll
            for (int xx = 0; xx < 8; ++xx) o[xx] = w0 * expf(-fabsf(ra[e][xx] - rb[e][xx]));
            *reinterpret_cast<float4*>(dt0 + base0 + (2 * yy + e) * W)     = make_float4(o[0], o[1], o[2], o[3]);
            *reinterpret_cast<float4*>(dt0 + base0 + (2 * yy + e) * W + 4) = make_float4(o[4], o[5], o[6], o[7]);
        }
        #pragma unroll
        for (int xx = 0; xx < 4; ++xx) {
            q1[yy][xx] = 0.25f * (ra[0][2 * xx] + ra[0][2 * xx + 1] + ra[1][2 * xx] + ra[1][2 * xx + 1]);
            q2[yy][xx] = 0.25f * (rb[0][2 * xx] + rb[0][2 * xx + 1] + rb[1][2 * xx] + rb[1][2 * xx + 1]);
        }
    }
    #pragma unroll
    for (int yy = 0; yy < 4; ++yy)
        #pragma unroll
        for (int xx = 0; xx < 4; ++xx)
            dt1[((size_t)b * 64 + ry * 4 + yy) * 96 + rx * 4 + xx] = w0 * expf(-fabsf(q1[yy][xx] - q2[yy][xx]));

    float r1[2][2], r2m[2][2];
    #pragma unroll
    for (int y = 0; y < 2; ++y)
        #pragma unroll
        for (int x = 0; x < 2; ++x) {
            r1[y][x]  = 0.25f * (q1[2 * y][2 * x] + q1[2 * y][2 * x + 1] + q1[2 * y + 1][2 * x] + q1[2 * y + 1][2 * x + 1]);
            r2m[y][x] = 0.25f * (q2[2 * y][2 * x] + q2[2 * y][2 * x + 1] + q2[2 * y + 1][2 * x] + q2[2 * y + 1][2 * x + 1]);
            dt2[((size_t)b * 32 + ry * 2 + y) * 48 + rx * 2 + x] = w0 * expf(-fabsf(r1[y][x] - r2m[y][x]));
        }
    float s1 = 0.25f * (r1[0][0] + r1[0][1] + r1[1][0] + r1[1][1]);
    float s2 = 0.25f * (r2m[0][0] + r2m[0][1] + r2m[1][0] + r2m[1][1]);
    dt3[((size_t)b * 16 + ry) * 24 + rx] = w0 * expf(-fabsf(s1 - s2));
}

// =====================================================================
extern "C" void kernel_launch(void* const* d_in, const int* in_sizes, int n_in,
                              void* d_out, int out_size, void* d_ws, size_t ws_size,
                              hipStream_t stream) {
    const float* f1 = (const float*)d_in[0];
    const float* f2 = (const float*)d_in[1];
    const float* d1 = (const float*)d_in[2];
    const float* d2 = (const float*)d_in[3];
    const float* dw = (const float*)d_in[4];
    float* out = (float*)d_out;
    float* ws  = (float*)d_ws;

    // ---------------- float workspace carve ----------------
    size_t o = 0;
    float* in1_0 = ws + o; o += (size_t)4 * 128 * 192;
    float* in1_1 = ws + o; o += (size_t)4 * 64 * 96;
    float* in1_2 = ws + o; o += (size_t)4 * 32 * 48;
    float* in1_3 = ws + o; o += (size_t)4 * 16 * 24;
    float* in2_0 = ws + o; o += (size_t)4 * 128 * 192;
    float* in2_1 = ws + o; o += (size_t)4 * 64 * 96;
    float* in2_2 = ws + o; o += (size_t)4 * 32 * 48;
    float* in2_3 = ws + o; o += (size_t)4 * 16 * 24;
    float* dt_0 = ws + o; o += (size_t)4 * 128 * 192;
    float* dt_1 = ws + o; o += (size_t)4 * 64 * 96;
    float* dt_2 = ws + o; o += (size_t)4 * 32 * 48;
    float* dt_3 = ws + o; o += (size_t)4 * 16 * 24;
    o = (o + 7) & ~(size_t)7;

    // ---------------- bf16 (ushort) workspace carve ----------------
    ushort_t* sws = (ushort_t*)(ws + o);
    const size_t L0 = (size_t)4 * 128 * 192 * 256;
    const size_t L1 = (size_t)4 * 64 * 96 * 256;
    const size_t L2 = (size_t)4 * 32 * 48 * 256;
    const size_t L3 = (size_t)4 * 16 * 24 * 256;
    const size_t FT = L0 + L1 + L2 + L3;
    ushort_t* f1n0 = sws;
    ushort_t* f1n1 = f1n0 + L0;
    ushort_t* f1n2 = f1n1 + L1;
    ushort_t* f1n3 = f1n2 + L2;
    ushort_t* f2n0 = sws + FT;
    ushort_t* f2n1 = f2n0 + L0;
    ushort_t* f2n2 = f2n1 + L1;
    ushort_t* f2n3 = f2n2 + L2;
    ushort_t* zblk = sws + 2 * FT;
    size_t need = o * 4 + (2 * FT + 256) * 2;
    if (ws_size < need) return;   // proven sufficient in prior rounds

    hipMemsetAsync(zblk, 0, 512, stream);

    depth_kernel<<<dim3(6), 256, 0, stream>>>(d1, d2, dw, dt_0, dt_1, dt_2, dt_3);

    // fused pyramid prep: ONE kernel, both tensors, all 4 levels
    PrepPtrs Pa = { f1n0, f1n1, f1n2, f1n3, in1_0, in1_1, in1_2, in1_3 };
    PrepPtrs Pb = { f2n0, f2n1, f2n2, f2n3, in2_0, in2_1, in2_2, in2_3 };
    pyr_prep_kernel<<<dim3(384, 2), 256, 0, stream>>>(f1, f2, Pa, Pb);

    // correlation
    corr_mfma2_kernel<<<dim3(16 * 12 * 4), 256, 0, stream>>>(f1n0, f2n0, in1_0, in2_0, dt_0, out,           zblk, 128, 192, 12, 16);
    corr_mfma2_kernel<<<dim3( 8 *  6 * 4), 256, 0, stream>>>(f1n1, f2n1, in1_1, in2_1, dt_1, out + 7962624, zblk,  64,  96,  6,  8);
    corr_mfma2_kernel<<<dim3( 4 *  3 * 4), 256, 0, stream>>>(f1n2, f2n2, in1_2, in2_2, dt_2, out + 9953280, zblk,  32,  48,  3,  4);
    corr_mfma_kernel<<<dim3(96 / 4), 256, 0, stream>>>(f1n3, f2n3, in1_3, in2_3, dt_3, out + 10450944, 16, 24, 6, 4,
                                                       (int)(2 * FT - (size_t)(f2n3 - sws)));
}

// Round 6
// 279.634 us; speedup vs baseline: 1.0850x; 1.0850x over previous
//
#include <hip/hip_runtime.h>
#include <hip/hip_bf16.h>

typedef __attribute__((ext_vector_type(8))) __bf16 bf16x8;
typedef __attribute__((ext_vector_type(4))) float f32x4;
typedef unsigned short ushort_t;
typedef unsigned int uint_t;

#define CCH 256
#define BB 4

// kc-plane strides in shorts: level npix * 32 ch
#define NP32_0 3145728   // 4*128*192*32
#define NP32_1 786432    // 4*64*96*32
#define NP32_2 196608    // 4*32*48*32
#define NP32_3 49152     // 4*16*24*32

__device__ __forceinline__ ushort_t f2b(float v) {
    __hip_bfloat16 h = __float2bfloat16(v);
    return *reinterpret_cast<ushort_t*>(&h);
}

__device__ __forceinline__ void gload16(const void* g, void* l) {
    __builtin_amdgcn_global_load_lds(
        (const __attribute__((address_space(1))) void*)g,
        (__attribute__((address_space(3))) void*)l, 16, 0, 0);
}

struct PrepPtrs {
    ushort_t* o0; ushort_t* o1; ushort_t* o2; ushort_t* o3;
    float* n0; float* n1; float* n2; float* n3;
};

// =====================================================================
// pyr_prep v3: same LDS structure as v2 (conflict-free, verified), but
// bf16 outputs go to kc-blocked layout [kc][pixel][32ch] so the L0
// write is wave-contiguous full cache lines (fixes 341MB write ampl).
// =====================================================================
__global__ __launch_bounds__(256, 3) void pyr_prep_kernel(
    const float* __restrict__ fa, const float* __restrict__ fb,
    PrepPtrs Pa, PrepPtrs Pb)
{
    const int H = 128, W = 192;
    const int HW = H * W;
    const float* fin = blockIdx.y ? fb : fa;
    PrepPtrs P = blockIdx.y ? Pb : Pa;

    __shared__ float lds0[32 * 260];   // [c:32][p:256 pad->260]
    __shared__ float lds1[32 * 68];    // [c:32][q:64 pad->68]
    __shared__ float lds2[32 * 20];    // [c:32][s:16 pad->20]
    __shared__ float red[256];

    int xc = blockIdx.x % 6;
    int ys = (blockIdx.x / 6) % 16;
    int b  = blockIdx.x / 96;
    int gx0 = xc * 32, gy0 = ys * 8;
    int t = threadIdx.x;

    const float* gsrc[8];
    int lofs[8];
    #pragma unroll
    for (int j = 0; j < 8; ++j) {
        int e = t + 256 * j;
        int c = e >> 6, r = (e >> 3) & 7, x4 = e & 7;
        gsrc[j] = fin + ((size_t)(b * 256 + c) * H + gy0 + r) * W + gx0 + 4 * x4;
        lofs[j] = c * 260 + r * 32 + 4 * x4;
    }

    float4 stg[8];
    auto issue = [&](int kc) {
        #pragma unroll
        for (int j = 0; j < 8; ++j)
            stg[j] = *reinterpret_cast<const float4*>(gsrc[j] + (size_t)kc * (32 * HW));
    };

    float ssq0 = 0.f, ssq1 = 0.f, ssq2 = 0.f, ssq3 = 0.f;

    size_t p0g = (size_t)(b * H + gy0 + (t >> 5)) * W + gx0 + (t & 31);     // L0 pixel
    int wv = t >> 6, q = t & 63, qy = q >> 4, qx = q & 15;                  // L1
    size_t l1g = (size_t)(b * 64 + ys * 4 + qy) * 96 + xc * 16 + qx;
    int cb2 = t >> 4, sI = t & 15, sy2 = sI >> 3, sx2 = sI & 7;             // L2 (t<128)
    size_t l2g = (size_t)(b * 32 + ys * 2 + sy2) * 48 + xc * 8 + sx2;
    int cb3 = t >> 2, u3 = t & 3;                                           // L3 (t<32)
    size_t l3g = (size_t)(b * 16 + ys) * 24 + xc * 4 + u3;

    issue(0);
    #pragma unroll 1
    for (int kc = 0; kc < 8; ++kc) {
        // ---- A: regs -> lds0 (b128, conflict-free) ----
        #pragma unroll
        for (int j = 0; j < 8; ++j)
            *reinterpret_cast<float4*>(&lds0[lofs[j]]) = stg[j];
        if (kc < 7) issue(kc + 1);
        __syncthreads();

        // ---- B: L0 bf16 (blocked layout: kc-plane + pixel*32) ----
        {
            uint_t uu[16];
            #pragma unroll
            for (int i = 0; i < 16; ++i) {
                float va = lds0[(2 * i) * 260 + t];
                float vb = lds0[(2 * i + 1) * 260 + t];
                ssq0 = fmaf(va, va, ssq0);
                ssq0 = fmaf(vb, vb, ssq0);
                uu[i] = (uint_t)f2b(va) | ((uint_t)f2b(vb) << 16);
            }
            ushort_t* dst = P.o0 + (size_t)kc * NP32_0 + p0g * 32;
            *reinterpret_cast<uint4*>(dst +  0) = make_uint4(uu[0],  uu[1],  uu[2],  uu[3]);
            *reinterpret_cast<uint4*>(dst +  8) = make_uint4(uu[4],  uu[5],  uu[6],  uu[7]);
            *reinterpret_cast<uint4*>(dst + 16) = make_uint4(uu[8],  uu[9],  uu[10], uu[11]);
            *reinterpret_cast<uint4*>(dst + 24) = make_uint4(uu[12], uu[13], uu[14], uu[15]);
        }

        // ---- L1: 2x2 pool ----
        {
            float a8[8];
            #pragma unroll
            for (int h = 0; h < 8; ++h) {
                int c = wv * 8 + h;
                float2 s0 = *reinterpret_cast<const float2*>(&lds0[c * 260 + (2 * qy) * 32 + 2 * qx]);
                float2 s1 = *reinterpret_cast<const float2*>(&lds0[c * 260 + (2 * qy + 1) * 32 + 2 * qx]);
                a8[h] = 0.25f * (s0.x + s0.y + s1.x + s1.y);
                ssq1 = fmaf(a8[h], a8[h], ssq1);
            }
            uint_t vv[4];
            #pragma unroll
            for (int i = 0; i < 4; ++i)
                vv[i] = (uint_t)f2b(a8[2 * i]) | ((uint_t)f2b(a8[2 * i + 1]) << 16);
            *reinterpret_cast<uint4*>(P.o1 + (size_t)kc * NP32_1 + l1g * 32 + wv * 8)
                = make_uint4(vv[0], vv[1], vv[2], vv[3]);
            #pragma unroll
            for (int h = 0; h < 8; ++h)
                lds1[(wv * 8 + h) * 68 + q] = a8[h];
        }
        __syncthreads();

        // ---- L2: 2x2 pool (t<128) ----
        if (t < 128) {
            float a4[4];
            #pragma unroll
            for (int cc = 0; cc < 4; ++cc) {
                int c = cb2 * 4 + cc;
                float2 s0 = *reinterpret_cast<const float2*>(&lds1[c * 68 + (2 * sy2) * 16 + 2 * sx2]);
                float2 s1 = *reinterpret_cast<const float2*>(&lds1[c * 68 + (2 * sy2 + 1) * 16 + 2 * sx2]);
                a4[cc] = 0.25f * (s0.x + s0.y + s1.x + s1.y);
                ssq2 = fmaf(a4[cc], a4[cc], ssq2);
            }
            uint_t w0 = (uint_t)f2b(a4[0]) | ((uint_t)f2b(a4[1]) << 16);
            uint_t w1 = (uint_t)f2b(a4[2]) | ((uint_t)f2b(a4[3]) << 16);
            *reinterpret_cast<uint2*>(P.o2 + (size_t)kc * NP32_2 + l2g * 32 + cb2 * 4) = make_uint2(w0, w1);
            #pragma unroll
            for (int cc = 0; cc < 4; ++cc)
                lds2[(cb2 * 4 + cc) * 20 + sI] = a4[cc];
        }
        __syncthreads();

        // ---- L3: 2x2 pool (t<32) ----
        if (t < 32) {
            float a4[4];
            #pragma unroll
            for (int cc = 0; cc < 4; ++cc) {
                int c = cb3 * 4 + cc;
                float2 s0 = *reinterpret_cast<const float2*>(&lds2[c * 20 + 2 * u3]);
                float2 s1 = *reinterpret_cast<const float2*>(&lds2[c * 20 + 8 + 2 * u3]);
                a4[cc] = 0.25f * (s0.x + s0.y + s1.x + s1.y);
                ssq3 = fmaf(a4[cc], a4[cc], ssq3);
            }
            uint_t w0 = (uint_t)f2b(a4[0]) | ((uint_t)f2b(a4[1]) << 16);
            uint_t w1 = (uint_t)f2b(a4[2]) | ((uint_t)f2b(a4[3]) << 16);
            *reinterpret_cast<uint2*>(P.o3 + (size_t)kc * NP32_3 + l3g * 32 + cb3 * 4) = make_uint2(w0, w1);
        }
    }

    // ---- invnorm reductions ----
    P.n0[p0g] = 1.f / fmaxf(sqrtf(ssq0), 1e-12f);
    red[t] = ssq1;
    __syncthreads();
    if (t < 64) {
        float sm = red[t] + red[t + 64] + red[t + 128] + red[t + 192];
        P.n1[(size_t)(b * 64 + ys * 4 + (t >> 4)) * 96 + xc * 16 + (t & 15)]
            = 1.f / fmaxf(sqrtf(sm), 1e-12f);
    }
    __syncthreads();
    if (t < 128) red[t] = ssq2;
    __syncthreads();
    if (t < 16) {
        float sm = 0.f;
        #pragma unroll
        for (int c = 0; c < 8; ++c) sm += red[t + 16 * c];
        P.n2[(size_t)(b * 32 + ys * 2 + (t >> 3)) * 48 + xc * 8 + (t & 7)]
            = 1.f / fmaxf(sqrtf(sm), 1e-12f);
    }
    __syncthreads();
    if (t < 32) red[t] = ssq3;
    __syncthreads();
    if (t < 4) {
        float sm = 0.f;
        #pragma unroll
        for (int c = 0; c < 8; ++c) sm += red[t + 4 * c];
        P.n3[(size_t)(b * 16 + ys) * 24 + xc * 4 + t]
            = 1.f / fmaxf(sqrtf(sm), 1e-12f);
    }
}

// =====================================================================
// corr_mfma2: LDS-staged, double-buffered; kc-blocked input layout
// (base = pix*32 + kgs*8, per-kc advance = npix32)
// =====================================================================
__global__ __launch_bounds__(256, 2) void corr_mfma2_kernel(
    const ushort_t* __restrict__ f1n, const ushort_t* __restrict__ f2n,
    const float* __restrict__ invn1, const float* __restrict__ invn2,
    const float* __restrict__ dt, float* __restrict__ out,
    const ushort_t* __restrict__ zblk, int H, int W, int TX, int TY, int npix32)
{
    __shared__ char smem[65536];
    char* As = smem;
    char* Bs = smem + 16384;

    int bid = blockIdx.x;
    int cpx = gridDim.x >> 3;
    int swz = (bid & 7) * cpx + (bid >> 3);
    int tx = swz % TX;
    int ty = (swz / TX) % TY;
    int b  = swz / (TX * TY);
    int x0 = tx * 16, y0 = ty * 8;

    int tid = threadIdx.x;
    int w = tid >> 6, lane = tid & 63;
    int kg = lane >> 4, col = lane & 15;
    int r2 = col >> 2, c2 = col & 3;
    int sy = w >> 1, p = w & 1;

    const ushort_t* srcA[2]; char* ldsA[2];
    #pragma unroll
    for (int q = 0; q < 2; ++q) {
        int qq = w * 2 + q;
        int kgs = qq >> 1, reg = qq & 1;
        int slot = reg * 64 + lane;
        int ly = slot >> 4, lxp = slot & 15;
        int lx = lxp ^ (4 * (ly & 1));
        srcA[q] = f1n + ((size_t)((b * H + y0 + ly) * W) + x0 + lx) * 32 + kgs * 8;
        ldsA[q] = As + qq * 1024;
    }
    const ushort_t* srcB[6]; int advB[6]; char* ldsB[6];
    #pragma unroll
    for (int q = 0; q < 6; ++q) {
        int qq = w * 6 + q;
        int kgs = qq / 6, reg = qq % 6;
        int slot = reg * 64 + lane;
        int wy = slot / 24, wxp = slot % 24;
        int wx = wxp ^ (4 * (wy & 1));
        int py = y0 - 4 + wy, px = x0 - 4 + wx;
        bool v = (py >= 0) && (py < H) && (px >= 0) && (px < W);
        srcB[q] = v ? (f2n + ((size_t)((b * H + py) * W) + px) * 32 + kgs * 8) : zblk;
        advB[q] = v ? npix32 : 0;
        ldsB[q] = Bs + qq * 1024;
    }

    int aoff[2], boff[3][4];
    #pragma unroll
    for (int s = 0; s < 2; ++s) {
        int sxs = 2 * p + s;
        int ly = 4 * sy + r2;
        int lx = (4 * sxs + c2) ^ (4 * (ly & 1));
        aoff[s] = kg * 2048 + (ly * 16 + lx) * 16;
    }
    #pragma unroll
    for (int i = 0; i < 3; ++i)
        #pragma unroll
        for (int j = 0; j < 4; ++j) {
            int wy = 4 * (sy + i) + r2;
            int wx = (4 * (2 * p + j) + c2) ^ (4 * (wy & 1));
            boff[i][j] = kg * 6144 + (wy * 24 + wx) * 16;
        }

    f32x4 acc0[3][3] = {};
    f32x4 acc1[3][3] = {};

    #pragma unroll
    for (int q = 0; q < 2; ++q) { gload16(srcA[q], ldsA[q]); srcA[q] += npix32; }
    #pragma unroll
    for (int q = 0; q < 6; ++q) { gload16(srcB[q], ldsB[q]); srcB[q] += advB[q]; }
    asm volatile("s_waitcnt vmcnt(0)" ::: "memory");
    __builtin_amdgcn_s_barrier();
    __builtin_amdgcn_sched_barrier(0);

    int buf = 0;
    #pragma unroll 1
    for (int kc = 0; kc < 8; ++kc) {
        if (kc < 7) {
            int boA = (buf ^ 1) * 8192;
            int boB = (buf ^ 1) * 24576;
            #pragma unroll
            for (int q = 0; q < 2; ++q) { gload16(srcA[q], ldsA[q] + boA); srcA[q] += npix32; }
            #pragma unroll
            for (int q = 0; q < 6; ++q) { gload16(srcB[q], ldsB[q] + boB); srcB[q] += advB[q]; }
        }
        const char* Ab = As + buf * 8192;
        const char* Bb = Bs + buf * 24576;
        bf16x8 av0 = *(const bf16x8*)(Ab + aoff[0]);
        bf16x8 av1 = *(const bf16x8*)(Ab + aoff[1]);
        #pragma unroll
        for (int i = 0; i < 3; ++i) {
            #pragma unroll
            for (int j = 0; j < 4; ++j) {
                bf16x8 bv = *(const bf16x8*)(Bb + boff[i][j]);
                if (j < 3) acc0[i][j]     = __builtin_amdgcn_mfma_f32_16x16x32_bf16(av0, bv, acc0[i][j], 0, 0, 0);
                if (j > 0) acc1[i][j - 1] = __builtin_amdgcn_mfma_f32_16x16x32_bf16(av1, bv, acc1[i][j - 1], 0, 0, 0);
            }
        }
        if (kc < 7) {
            __builtin_amdgcn_sched_barrier(0);
            asm volatile("s_waitcnt vmcnt(0)" ::: "memory");
            __builtin_amdgcn_s_barrier();
            __builtin_amdgcn_sched_barrier(0);
        }
        buf ^= 1;
    }

    float inv1v[2][4], dtv[2][4];
    #pragma unroll
    for (int s = 0; s < 2; ++s) {
        int sxs = 2 * p + s;
        #pragma unroll
        for (int rr = 0; rr < 4; ++rr) {
            int m = kg * 4 + rr;
            int iy = m >> 2, ix = m & 3;
            int pix = (b * H + y0 + 4 * sy + iy) * W + x0 + 4 * sxs + ix;
            inv1v[s][rr] = invn1[pix];
            dtv[s][rr]   = dt[pix];
        }
    }
    #pragma unroll
    for (int s = 0; s < 2; ++s) {
        int sxs = 2 * p + s;
        #pragma unroll
        for (int i = 0; i < 3; ++i) {
            #pragma unroll
            for (int jj = 0; jj < 3; ++jj) {
                int wy = 4 * (sy + i) + r2;
                int wxr = 4 * (sxs + jj) + c2;
                int py = y0 - 4 + wy, px = x0 - 4 + wxr;
                bool v = (py >= 0) && (py < H) && (px >= 0) && (px < W);
                float i2 = v ? invn2[(b * H + py) * W + px] : 0.f;
                f32x4 a = (s == 0) ? acc0[i][jj] : acc1[i][jj];
                #pragma unroll
                for (int rr = 0; rr < 4; ++rr) {
                    int m = kg * 4 + rr;
                    int iy = m >> 2, ix = m & 3;
                    int oy = iy + 8 - (4 * i + r2);
                    int ox = ix + 8 - (4 * jj + c2);
                    if (oy >= 0 && oy < 9 && ox >= 0 && ox < 9) {
                        int gy = y0 + 4 * sy + iy, gx = x0 + 4 * sxs + ix;
                        out[((size_t)(b * 81 + oy * 9 + ox) * H + gy) * W + gx]
                            = a[rr] * inv1v[s][rr] * i2 + dtv[s][rr];
                    }
                }
            }
        }
    }
}

// =====================================================================
// corr_mfma — L3 only, kc-blocked layout
// =====================================================================
__global__ __launch_bounds__(256) void corr_mfma_kernel(
    const ushort_t* __restrict__ f1n, const ushort_t* __restrict__ f2n,
    const float* __restrict__ invn1, const float* __restrict__ invn2,
    const float* __restrict__ dt, float* __restrict__ out,
    int H, int W, int TX, int TY, int zoff)
{
    int wid  = threadIdx.x >> 6;
    int lane = threadIdx.x & 63;
    int tile = blockIdx.x * 4 + wid;
    int ntiles = BB * TY * TX;
    if (tile >= ntiles) return;
    int tx = tile % TX;
    int ty = (tile / TX) % TY;
    int b  = tile / (TX * TY);
    int x0 = tx * 4, y0 = ty * 4;

    int col = lane & 15;
    int kg  = lane >> 4;

    int iyA = col >> 2, ixA = col & 3;
    int a_off = (((b * H + y0 + iyA) * W) + x0 + ixA) * 32 + kg * 8;

    int b_off[9], badv[9];
    uint_t vmask = 0;
    #pragma unroll
    for (int tt = 0; tt < 9; ++tt) {
        int w = tt * 16 + col;
        int wy = w / 12, wx = w % 12;
        int py = y0 + wy - 4, px = x0 + wx - 4;
        bool v = (py >= 0) && (py < H) && (px >= 0) && (px < W);
        b_off[tt] = v ? (((b * H + py) * W + px) * 32 + kg * 8) : (zoff + kg * 8);
        badv[tt] = v ? NP32_3 : 0;
        if (v) vmask |= (1u << tt);
    }

    f32x4 acc[9] = {};
    #pragma unroll
    for (int kb = 0; kb < 8; ++kb) {
        bf16x8 av = *reinterpret_cast<const bf16x8*>(f1n + a_off + kb * NP32_3);
        #pragma unroll
        for (int tt = 0; tt < 9; ++tt) {
            bf16x8 bv = *reinterpret_cast<const bf16x8*>(f2n + b_off[tt]);
            acc[tt] = __builtin_amdgcn_mfma_f32_16x16x32_bf16(av, bv, acc[tt], 0, 0, 0);
            b_off[tt] += badv[tt];
        }
    }

    float inv1[4], dts[4];
    #pragma unroll
    for (int r = 0; r < 4; ++r) {
        int m = kg * 4 + r;
        int iy = m >> 2, ix = m & 3;
        int pix = (b * H + y0 + iy) * W + x0 + ix;
        inv1[r] = invn1[pix];
        dts[r]  = dt[pix];
    }
    #pragma unroll
    for (int tt = 0; tt < 9; ++tt) {
        int w = tt * 16 + col;
        int wy = w / 12, wx = w % 12;
        int py = y0 + wy - 4, px = x0 + wx - 4;
        float i2 = ((vmask >> tt) & 1u) ? invn2[(b * H + py) * W + px] : 0.f;
        #pragma unroll
        for (int r = 0; r < 4; ++r) {
            int m = kg * 4 + r;
            int iy = m >> 2, ix = m & 3;
            int oy = iy + 8 - wy, ox = ix + 8 - wx;
            if (oy >= 0 && oy < 9 && ox >= 0 && ox < 9) {
                int o = oy * 9 + ox;
                out[((size_t)(b * 81 + o) * H + (y0 + iy)) * W + (x0 + ix)]
                    = acc[tt][r] * inv1[r] * i2 + dts[r];
            }
        }
    }
}

// =====================================================================
// depth: one thread owns an 8x8 L0 patch; dt for all 4 levels
// =====================================================================
__global__ __launch_bounds__(256) void depth_kernel(
    const float* __restrict__ d1, const float* __restrict__ d2,
    const float* __restrict__ dw,
    float* __restrict__ dt0, float* __restrict__ dt1,
    float* __restrict__ dt2, float* __restrict__ dt3)
{
    int rid = blockIdx.x * 256 + threadIdx.x;
    if (rid >= 4 * 16 * 24) return;
    int b = rid / 384, rr = rid % 384, ry = rr / 24, rx = rr % 24;
    const int H = 128, W = 192;
    float w0 = dw[0];
    size_t base0 = ((size_t)b * H + ry * 8) * W + rx * 8;

    float q1[4][4], q2[4][4];
    #pragma unroll
    for (int yy = 0; yy < 4; ++yy) {
        float4 a0 = *reinterpret_cast<const float4*>(d1 + base0 + (2 * yy) * W);
        float4 a1 = *reinterpret_cast<const float4*>(d1 + base0 + (2 * yy) * W + 4);
        float4 a2 = *reinterpret_cast<const float4*>(d1 + base0 + (2 * yy + 1) * W);
        float4 a3 = *reinterpret_cast<const float4*>(d1 + base0 + (2 * yy + 1) * W + 4);
        float4 b0 = *reinterpret_cast<const float4*>(d2 + base0 + (2 * yy) * W);
        float4 b1 = *reinterpret_cast<const float4*>(d2 + base0 + (2 * yy) * W + 4);
        float4 b2 = *reinterpret_cast<const float4*>(d2 + base0 + (2 * yy + 1) * W);
        float4 b3 = *reinterpret_cast<const float4*>(d2 + base0 + (2 * yy + 1) * W + 4);
        float ra[2][8] = {{a0.x,a0.y,a0.z,a0.w,a1.x,a1.y,a1.z,a1.w},
                          {a2.x,a2.y,a2.z,a2.w,a3.x,a3.y,a3.z,a3.w}};
        float rb[2][8] = {{b0.x,b0.y,b0.z,b0.w,b1.x,b1.y,b1.z,b1.w},
                          {b2.x,b2.y,b2.z,b2.w,b3.x,b3.y,b3.z,b3.w}};
        #pragma unroll
        for (int e = 0; e < 2; ++e) {
            float o[8];
            #pragma unroll
            for (int xx = 0; xx < 8; ++xx) o[xx] = w0 * expf(-fabsf(ra[e][xx] - rb[e][xx]));
            *reinterpret_cast<float4*>(dt0 + base0 + (2 * yy + e) * W)     = make_float4(o[0], o[1], o[2], o[3]);
            *reinterpret_cast<float4*>(dt0 + base0 + (2 * yy + e) * W + 4) = make_float4(o[4], o[5], o[6], o[7]);
        }
        #pragma unroll
        for (int xx = 0; xx < 4; ++xx) {
            q1[yy][xx] = 0.25f * (ra[0][2 * xx] + ra[0][2 * xx + 1] + ra[1][2 * xx] + ra[1][2 * xx + 1]);
            q2[yy][xx] = 0.25f * (rb[0][2 * xx] + rb[0][2 * xx + 1] + rb[1][2 * xx] + rb[1][2 * xx + 1]);
        }
    }
    #pragma unroll
    for (int yy = 0; yy < 4; ++yy)
        #pragma unroll
        for (int xx = 0; xx < 4; ++xx)
            dt1[((size_t)b * 64 + ry * 4 + yy) * 96 + rx * 4 + xx] = w0 * expf(-fabsf(q1[yy][xx] - q2[yy][xx]));

    float r1[2][2], r2m[2][2];
    #pragma unroll
    for (int y = 0; y < 2; ++y)
        #pragma unroll
        for (int x = 0; x < 2; ++x) {
            r1[y][x]  = 0.25f * (q1[2 * y][2 * x] + q1[2 * y][2 * x + 1] + q1[2 * y + 1][2 * x] + q1[2 * y + 1][2 * x + 1]);
            r2m[y][x] = 0.25f * (q2[2 * y][2 * x] + q2[2 * y][2 * x + 1] + q2[2 * y + 1][2 * x] + q2[2 * y + 1][2 * x + 1]);
            dt2[((size_t)b * 32 + ry * 2 + y) * 48 + rx * 2 + x] = w0 * expf(-fabsf(r1[y][x] - r2m[y][x]));
        }
    float s1 = 0.25f * (r1[0][0] + r1[0][1] + r1[1][0] + r1[1][1]);
    float s2 = 0.25f * (r2m[0][0] + r2m[0][1] + r2m[1][0] + r2m[1][1]);
    dt3[((size_t)b * 16 + ry) * 24 + rx] = w0 * expf(-fabsf(s1 - s2));
}

// =====================================================================
extern "C" void kernel_launch(void* const* d_in, const int* in_sizes, int n_in,
                              void* d_out, int out_size, void* d_ws, size_t ws_size,
                              hipStream_t stream) {
    const float* f1 = (const float*)d_in[0];
    const float* f2 = (const float*)d_in[1];
    const float* d1 = (const float*)d_in[2];
    const float* d2 = (const float*)d_in[3];
    const float* dw = (const float*)d_in[4];
    float* out = (float*)d_out;
    float* ws  = (float*)d_ws;

    // ---------------- float workspace carve ----------------
    size_t o = 0;
    float* in1_0 = ws + o; o += (size_t)4 * 128 * 192;
    float* in1_1 = ws + o; o += (size_t)4 * 64 * 96;
    float* in1_2 = ws + o; o += (size_t)4 * 32 * 48;
    float* in1_3 = ws + o; o += (size_t)4 * 16 * 24;
    float* in2_0 = ws + o; o += (size_t)4 * 128 * 192;
    float* in2_1 = ws + o; o += (size_t)4 * 64 * 96;
    float* in2_2 = ws + o; o += (size_t)4 * 32 * 48;
    float* in2_3 = ws + o; o += (size_t)4 * 16 * 24;
    float* dt_0 = ws + o; o += (size_t)4 * 128 * 192;
    float* dt_1 = ws + o; o += (size_t)4 * 64 * 96;
    float* dt_2 = ws + o; o += (size_t)4 * 32 * 48;
    float* dt_3 = ws + o; o += (size_t)4 * 16 * 24;
    o = (o + 7) & ~(size_t)7;

    // ---------------- bf16 (ushort) workspace carve ----------------
    ushort_t* sws = (ushort_t*)(ws + o);
    const size_t L0 = (size_t)4 * 128 * 192 * 256;
    const size_t L1 = (size_t)4 * 64 * 96 * 256;
    const size_t L2 = (size_t)4 * 32 * 48 * 256;
    const size_t L3 = (size_t)4 * 16 * 24 * 256;
    const size_t FT = L0 + L1 + L2 + L3;
    ushort_t* f1n0 = sws;
    ushort_t* f1n1 = f1n0 + L0;
    ushort_t* f1n2 = f1n1 + L1;
    ushort_t* f1n3 = f1n2 + L2;
    ushort_t* f2n0 = sws + FT;
    ushort_t* f2n1 = f2n0 + L0;
    ushort_t* f2n2 = f2n1 + L1;
    ushort_t* f2n3 = f2n2 + L2;
    ushort_t* zblk = sws + 2 * FT;
    size_t need = o * 4 + (2 * FT + 256) * 2;
    if (ws_size < need) return;   // proven sufficient in prior rounds

    hipMemsetAsync(zblk, 0, 512, stream);

    depth_kernel<<<dim3(6), 256, 0, stream>>>(d1, d2, dw, dt_0, dt_1, dt_2, dt_3);

    PrepPtrs Pa = { f1n0, f1n1, f1n2, f1n3, in1_0, in1_1, in1_2, in1_3 };
    PrepPtrs Pb = { f2n0, f2n1, f2n2, f2n3, in2_0, in2_1, in2_2, in2_3 };
    pyr_prep_kernel<<<dim3(384, 2), 256, 0, stream>>>(f1, f2, Pa, Pb);

    corr_mfma2_kernel<<<dim3(16 * 12 * 4), 256, 0, stream>>>(f1n0, f2n0, in1_0, in2_0, dt_0, out,           zblk, 128, 192, 12, 16, NP32_0);
    corr_mfma2_kernel<<<dim3( 8 *  6 * 4), 256, 0, stream>>>(f1n1, f2n1, in1_1, in2_1, dt_1, out + 7962624, zblk,  64,  96,  6,  8, NP32_1);
    corr_mfma2_kernel<<<dim3( 4 *  3 * 4), 256, 0, stream>>>(f1n2, f2n2, in1_2, in2_2, dt_2, out + 9953280, zblk,  32,  48,  3,  4, NP32_2);
    corr_mfma_kernel<<<dim3(96 / 4), 256, 0, stream>>>(f1n3, f2n3, in1_3, in2_3, dt_3, out + 10450944, 16, 24, 6, 4,
                                                       (int)(2 * FT - (size_t)(f2n3 - sws)));
}